// Round 1
// baseline (504.028 us; speedup 1.0000x reference)
//
#include <hip/hip_runtime.h>

// TransformerLayer on MI355X (gfx950), bf16 MFMA pipeline, fp32 LN/softmax/accum.
// Workspace budget ~116 MB (hb aliases qkvb+ob). All launches on `stream`,
// no alloc/sync (graph-capture safe). Everything read from d_ws is written
// earlier in the same launch (d_ws is re-poisoned to 0xAA each call).

typedef unsigned short u16;
typedef unsigned int   u32;
typedef __bf16 bf16x8 __attribute__((ext_vector_type(8)));
typedef float  f32x4  __attribute__((ext_vector_type(4)));

#define NEG_INF (-__builtin_inff())

// fp32 -> bf16 RNE (finite inputs only)
__device__ __forceinline__ u16 f2b(float f) {
  u32 u = __float_as_uint(f);
  u = (u + 0x7fffu + ((u >> 16) & 1u)) >> 16;
  return (u16)u;
}

// async global->LDS, 16B per lane. LDS dest must be wave-uniform base + lane*16.
__device__ __forceinline__ void gload16(const void* g, void* l) {
  __builtin_amdgcn_global_load_lds(
      (const __attribute__((address_space(1))) u32*)g,
      (__attribute__((address_space(3))) u32*)l, 16, 0, 0);
}

// ---------------------------------------------------------------------------
// Weight transpose + fp32->bf16. in: [z][R][C] fp32 row-major.
// out element (z,c,r) at out[(z*C + c)*R + r]  (i.e. [N][K] per matrix).
__global__ __launch_bounds__(256)
void transpose_bf16_k(const float* __restrict__ in, u16* __restrict__ out,
                      int R, int C) {
  __shared__ float tile[64][65];
  int r0 = blockIdx.x * 64, c0 = blockIdx.y * 64;
  const float* ip = in + (size_t)blockIdx.z * R * C;
  u16* op = out + (size_t)blockIdx.z * C * R;
  int tr = threadIdx.x >> 6, tc = threadIdx.x & 63;
#pragma unroll
  for (int i = 0; i < 16; i++) {
    int r = i * 4 + tr;
    tile[r][tc] = ip[(size_t)(r0 + r) * C + c0 + tc];
  }
  __syncthreads();
#pragma unroll
  for (int i = 0; i < 16; i++) {
    int c = i * 4 + tr;
    op[(size_t)(c0 + c) * R + r0 + tc] = f2b(tile[tc][c]);
  }
}

// ---------------------------------------------------------------------------
// LayerNorm over rows of 1024. Optional second input (residual add) and
// optional fp32 output; always writes bf16 output.
__global__ __launch_bounds__(256)
void ln_k(const float* __restrict__ in, const float* __restrict__ in2,
          const float* __restrict__ w, const float* __restrict__ b,
          float* __restrict__ outf, u16* __restrict__ outb) {
  int row = blockIdx.x, t = threadIdx.x;
  const float4* ip = (const float4*)(in + (size_t)row * 1024);
  float4 x = ip[t];
  if (in2) {
    const float4* ip2 = (const float4*)(in2 + (size_t)row * 1024);
    float4 o = ip2[t];
    x.x += o.x; x.y += o.y; x.z += o.z; x.w += o.w;
  }
  float s = x.x + x.y + x.z + x.w;
  float q = x.x * x.x + x.y * x.y + x.z * x.z + x.w * x.w;
#pragma unroll
  for (int m = 32; m; m >>= 1) { s += __shfl_xor(s, m); q += __shfl_xor(q, m); }
  __shared__ float rs[4], rq[4];
  if ((t & 63) == 0) { rs[t >> 6] = s; rq[t >> 6] = q; }
  __syncthreads();
  s = rs[0] + rs[1] + rs[2] + rs[3];
  q = rq[0] + rq[1] + rq[2] + rq[3];
  float mean = s * (1.f / 1024.f);
  float var  = q * (1.f / 1024.f) - mean * mean;
  float rstd = rsqrtf(var + 1e-5f);
  float4 wv = ((const float4*)w)[t];
  float4 bv = ((const float4*)b)[t];
  float4 y;
  y.x = (x.x - mean) * rstd * wv.x + bv.x;
  y.y = (x.y - mean) * rstd * wv.y + bv.y;
  y.z = (x.z - mean) * rstd * wv.z + bv.z;
  y.w = (x.w - mean) * rstd * wv.w + bv.w;
  if (outf) ((float4*)(outf + (size_t)row * 1024))[t] = y;
  ushort4 ub;
  ub.x = f2b(y.x); ub.y = f2b(y.y); ub.z = f2b(y.z); ub.w = f2b(y.w);
  ((ushort4*)(outb + (size_t)row * 1024))[t] = ub;
}

// ---------------------------------------------------------------------------
// 128x128 tile bf16 GEMM, BK=32, 256 threads (4 waves, 2x2 of 64x64 each).
// A: [M][K] bf16 row-major (lda). Bt: [N][K] bf16 row-major (ldbt).
// Epilogues: QKV scatter / bias+relu->bf16 / bias+residual->fp32.
#define EPI_QKV  0
#define EPI_RELU 1
#define EPI_RES  2

template <int EPI>
__global__ __launch_bounds__(256)
void gemm_k(const u16* __restrict__ A, const u16* __restrict__ Bt,
            int K, int lda, int ldbt,
            const float* __restrict__ bias0, const float* __restrict__ bias1,
            const float* __restrict__ bias2, const float* __restrict__ res,
            int ldout, u16* __restrict__ outb, float* __restrict__ outf) {
  __shared__ __align__(16) u16 As[128 * 32];
  __shared__ __align__(16) u16 Bs[128 * 32];
  int t = threadIdx.x;
  int wave = t >> 6, lane = t & 63, quad = lane >> 4, l16 = lane & 15;
  int wm = (wave >> 1) * 64, wn = (wave & 1) * 64;
  int bm = blockIdx.x * 128, bn = blockIdx.y * 128;

  const u16* Ag = A + (size_t)(bm + (t >> 2)) * lda + (t & 3) * 8;
  const u16* Bg = Bt + (size_t)(bn + (t >> 2)) * ldbt + (t & 3) * 8;
  u16* Asl = As + t * 8;
  u16* Bsl = Bs + t * 8;

  f32x4 acc[4][4] = {};

  for (int k0 = 0; k0 < K; k0 += 32) {
    gload16(Ag + k0, Asl);
    gload16(Ag + k0 + (size_t)64 * lda, Asl + 2048);
    gload16(Bg + k0, Bsl);
    gload16(Bg + k0 + (size_t)64 * ldbt, Bsl + 2048);
    __syncthreads();
    bf16x8 af[4], bfr[4];
#pragma unroll
    for (int i = 0; i < 4; i++)
      af[i] = *(const bf16x8*)(As + (wm + i * 16 + l16) * 32 + quad * 8);
#pragma unroll
    for (int j = 0; j < 4; j++)
      bfr[j] = *(const bf16x8*)(Bs + (wn + j * 16 + l16) * 32 + quad * 8);
#pragma unroll
    for (int i = 0; i < 4; i++)
#pragma unroll
      for (int j = 0; j < 4; j++)
        acc[i][j] = __builtin_amdgcn_mfma_f32_16x16x32_bf16(af[i], bfr[j],
                                                            acc[i][j], 0, 0, 0);
    __syncthreads();
  }

#pragma unroll
  for (int i = 0; i < 4; i++) {
#pragma unroll
    for (int j = 0; j < 4; j++) {
      int c = bn + wn + j * 16 + l16;
#pragma unroll
      for (int rr = 0; rr < 4; rr++) {
        int r = bm + wm + i * 16 + quad * 4 + rr;
        float v = acc[i][j][rr];
        if (EPI == EPI_QKV) {
          int which = c >> 10, h = (c >> 6) & 15, d = c & 63;
          const float* bp = which == 0 ? bias0 : (which == 1 ? bias1 : bias2);
          v += bp[h * 64 + d];
          int bb = r >> 11, ss = r & 2047;
          outb[((size_t)(which * 32 + bb * 16 + h) * 2048 + ss) * 64 + d] = f2b(v);
        } else if (EPI == EPI_RELU) {
          v += bias0[c];
          v = v > 0.f ? v : 0.f;
          outb[(size_t)r * ldout + c] = f2b(v);
        } else {
          v += bias0[c] + res[(size_t)r * ldout + c];
          outf[(size_t)r * ldout + c] = v;
        }
      }
    }
  }
}

// ---------------------------------------------------------------------------
// Flash attention, causal. Grid (S/64, B*H). Block 256 (4 waves).
// qkv: [which][b][h][s][64] bf16.  o: [B][S][1024] fp32 (head-concat).
__global__ __launch_bounds__(256)
void attn_k(const u16* __restrict__ qkv, float* __restrict__ o) {
  int qt = blockIdx.x, bh = blockIdx.y;
  int b = bh >> 4, h = bh & 15;
  const u16* qg = qkv + (size_t)bh * (2048 * 64);
  const u16* kg = qkv + (size_t)(32 + bh) * (2048 * 64);
  const u16* vg = qkv + (size_t)(64 + bh) * (2048 * 64);

  __shared__ __align__(16) u16 Qs[64 * 64];
  __shared__ __align__(16) u16 Ks[64 * 64];
  __shared__ __align__(16) u16 Vt[64 * 72];  // [dh][kv], rows padded to 72 (144B, 16B-aligned)
  __shared__ __align__(16) float Sc[64 * 64];
  __shared__ __align__(16) u16 Pb[64 * 64];
  __shared__ float m_s[64], l_s[64], al_s[64];

  int t = threadIdx.x, wave = t >> 6, lane = t & 63, quad = lane >> 4, l16 = lane & 15;

  {
    const u16* Qp = qg + (size_t)(qt * 64 + (t >> 3)) * 64 + (t & 7) * 8;
    gload16(Qp, Qs + t * 8);
    gload16(Qp + 32 * 64, Qs + t * 8 + 2048);
  }
  if (t < 64) { m_s[t] = NEG_INF; l_s[t] = 0.f; }
  __syncthreads();

  bf16x8 qf[4][2];
#pragma unroll
  for (int mt = 0; mt < 4; mt++)
#pragma unroll
    for (int kc = 0; kc < 2; kc++)
      qf[mt][kc] = *(const bf16x8*)(Qs + (mt * 16 + l16) * 64 + kc * 32 + quad * 8);

  f32x4 oacc[4] = {};

  for (int kt = 0; kt <= qt; kt++) {
    // stage K tile (async) and V tile transposed (manual)
    const u16* Kp = kg + (size_t)(kt * 64 + (t >> 3)) * 64 + (t & 7) * 8;
    gload16(Kp, Ks + t * 8);
    gload16(Kp + 32 * 64, Ks + t * 8 + 2048);
    {
      const u16* Vp = vg + (size_t)(kt * 64) * 64;
#pragma unroll
      for (int it = 0; it < 2; it++) {
        int vr = (t >> 3) + it * 32;
        int vc = (t & 7) * 8;
        uint4 dv = *(const uint4*)(Vp + (size_t)vr * 64 + vc);
        const u16* ev = (const u16*)&dv;
#pragma unroll
        for (int j = 0; j < 8; j++) Vt[(vc + j) * 72 + vr] = ev[j];
      }
    }
    __syncthreads();

    // S = Q K^T strip: wave handles kv cols [wave*16, wave*16+16)
    bf16x8 kf[2];
#pragma unroll
    for (int kc = 0; kc < 2; kc++)
      kf[kc] = *(const bf16x8*)(Ks + (wave * 16 + l16) * 64 + kc * 32 + quad * 8);
#pragma unroll
    for (int mt = 0; mt < 4; mt++) {
      f32x4 sc = {};
#pragma unroll
      for (int kc = 0; kc < 2; kc++)
        sc = __builtin_amdgcn_mfma_f32_16x16x32_bf16(qf[mt][kc], kf[kc], sc, 0, 0, 0);
      int col = kt * 64 + wave * 16 + l16;
#pragma unroll
      for (int rr = 0; rr < 4; rr++) {
        int lr = mt * 16 + quad * 4 + rr;
        int row = qt * 64 + lr;
        Sc[lr * 64 + wave * 16 + l16] = (col <= row) ? sc[rr] * 0.125f : NEG_INF;
      }
    }
    __syncthreads();

    // online softmax: thread -> (row = t>>2, 16-col segment = t&3)
    {
      int row = t >> 2, seg = t & 3;
      float mold = m_s[row];
      const float4* sr = (const float4*)(Sc + row * 64 + seg * 16);
      float evv[16];
      ((float4*)evv)[0] = sr[0]; ((float4*)evv)[1] = sr[1];
      ((float4*)evv)[2] = sr[2]; ((float4*)evv)[3] = sr[3];
      float mx = NEG_INF;
#pragma unroll
      for (int j = 0; j < 16; j++) mx = fmaxf(mx, evv[j]);
      mx = fmaxf(mx, __shfl_xor(mx, 1));
      mx = fmaxf(mx, __shfl_xor(mx, 2));
      float mnew = fmaxf(mold, mx);
      float sum = 0.f;
      u16* pr = Pb + row * 64 + seg * 16;
#pragma unroll
      for (int j = 0; j < 16; j++) {
        float p = __expf(evv[j] - mnew);   // masked (-inf) -> 0
        sum += p;
        pr[j] = f2b(p);
      }
      sum += __shfl_xor(sum, 1);
      sum += __shfl_xor(sum, 2);
      if (seg == 0) {
        float alpha = __expf(mold - mnew); // first tile: exp(-inf)=0
        m_s[row] = mnew;
        l_s[row] = l_s[row] * alpha + sum;
        al_s[row] = alpha;
      }
    }
    __syncthreads();

    // rescale O, then O += P @ V
#pragma unroll
    for (int mt = 0; mt < 4; mt++)
#pragma unroll
      for (int rr = 0; rr < 4; rr++)
        oacc[mt][rr] *= al_s[mt * 16 + quad * 4 + rr];
    bf16x8 vf[2];
#pragma unroll
    for (int kc = 0; kc < 2; kc++)
      vf[kc] = *(const bf16x8*)(Vt + (wave * 16 + l16) * 72 + kc * 32 + quad * 8);
#pragma unroll
    for (int mt = 0; mt < 4; mt++)
#pragma unroll
      for (int kc = 0; kc < 2; kc++) {
        bf16x8 pf = *(const bf16x8*)(Pb + (mt * 16 + l16) * 64 + kc * 32 + quad * 8);
        oacc[mt] = __builtin_amdgcn_mfma_f32_16x16x32_bf16(pf, vf[kc], oacc[mt], 0, 0, 0);
      }
    __syncthreads();
  }

  // normalize and write O (head-concat layout)
#pragma unroll
  for (int mt = 0; mt < 4; mt++)
#pragma unroll
    for (int rr = 0; rr < 4; rr++) {
      int lr = mt * 16 + quad * 4 + rr;
      float val = oacc[mt][rr] / l_s[lr];
      int srow = qt * 64 + lr;
      int col = h * 64 + wave * 16 + l16;
      o[((size_t)b * 2048 + srow) * 1024 + col] = val;
    }
}

// ---------------------------------------------------------------------------
extern "C" void kernel_launch(void* const* d_in, const int* in_sizes, int n_in,
                              void* d_out, int out_size, void* d_ws, size_t ws_size,
                              hipStream_t stream) {
  const float* emb  = (const float*)d_in[0];
  const float* Wq   = (const float*)d_in[1];
  const float* bq   = (const float*)d_in[2];
  const float* Wk   = (const float*)d_in[3];
  const float* bk   = (const float*)d_in[4];
  const float* Wv   = (const float*)d_in[5];
  const float* bv   = (const float*)d_in[6];
  const float* ln1w = (const float*)d_in[7];
  const float* ln1b = (const float*)d_in[8];
  const float* ln2w = (const float*)d_in[9];
  const float* ln2b = (const float*)d_in[10];
  const float* W1   = (const float*)d_in[11];
  const float* b1   = (const float*)d_in[12];
  const float* W2   = (const float*)d_in[13];
  const float* b2   = (const float*)d_in[14];
  float* out = (float*)d_out;

  char* p = (char*)d_ws;
  u16*   Wqkv_t = (u16*)p;   p += (size_t)3072 * 1024 * 2;
  u16*   W1t    = (u16*)p;   p += (size_t)4096 * 1024 * 2;
  u16*   W2t    = (u16*)p;   p += (size_t)1024 * 4096 * 2;
  float* x      = (float*)p; p += (size_t)4096 * 1024 * 4;
  u16*   xb     = (u16*)p;   p += (size_t)4096 * 1024 * 2;
  u16*   qkvb   = (u16*)p;   p += (size_t)3 * 32 * 2048 * 64 * 2;  // 25.2 MB
  float* ob     = (float*)p; p += (size_t)4096 * 1024 * 4;         // 16.8 MB
  float* y      = (float*)p; p += (size_t)4096 * 1024 * 4;
  u16*   yb     = (u16*)p;   p += (size_t)4096 * 1024 * 2;
  u16*   hb     = (u16*)qkvb; // alias: qkvb+ob (42 MB) dead before FFN1 writes hb (33.6 MB)
  if (ws_size < (size_t)(p - (char*)d_ws)) return;

  // weight transposes (d_ws poisoned each call -> must rebuild every launch)
  transpose_bf16_k<<<dim3(16, 1, 16), 256, 0, stream>>>(Wq, Wqkv_t,                   1024, 64);
  transpose_bf16_k<<<dim3(16, 1, 16), 256, 0, stream>>>(Wk, Wqkv_t + 1024 * 1024,     1024, 64);
  transpose_bf16_k<<<dim3(16, 1, 16), 256, 0, stream>>>(Wv, Wqkv_t + 2 * 1024 * 1024, 1024, 64);
  transpose_bf16_k<<<dim3(16, 64, 1), 256, 0, stream>>>(W1, W1t, 1024, 4096);
  transpose_bf16_k<<<dim3(64, 16, 1), 256, 0, stream>>>(W2, W2t, 4096, 1024);

  ln_k<<<dim3(4096), 256, 0, stream>>>(emb, nullptr, ln1w, ln1b, x, xb);

  gemm_k<EPI_QKV><<<dim3(32, 24), 256, 0, stream>>>(
      xb, Wqkv_t, 1024, 1024, 1024, bq, bk, bv, nullptr, 0, qkvb, nullptr);

  attn_k<<<dim3(32, 32), 256, 0, stream>>>(qkvb, ob);

  ln_k<<<dim3(4096), 256, 0, stream>>>(x, ob, ln2w, ln2b, y, yb);

  gemm_k<EPI_RELU><<<dim3(32, 32), 256, 0, stream>>>(
      yb, W1t, 1024, 1024, 1024, b1, nullptr, nullptr, nullptr, 4096, hb, nullptr);

  gemm_k<EPI_RES><<<dim3(32, 8), 256, 0, stream>>>(
      hb, W2t, 4096, 4096, 4096, b2, nullptr, nullptr, y, 1024, nullptr, out);
}

// Round 2
// 393.923 us; speedup vs baseline: 1.2795x; 1.2795x over previous
//
#include <hip/hip_runtime.h>

// TransformerLayer on MI355X (gfx950), bf16 MFMA pipeline, fp32 LN/softmax/accum.
// R2: attention rewritten — 8-wave blocks, in-register online softmax,
// per-wave P transpose (no barrier), swizzled LDS (conflict-free b128 reads),
// double-buffered K/V staging, pre-transposed V, balanced causal pairing.

typedef unsigned short u16;
typedef unsigned int   u32;
typedef __bf16 bf16x8 __attribute__((ext_vector_type(8)));
typedef float  f32x4  __attribute__((ext_vector_type(4)));

#define NEG_INF (-__builtin_inff())

// fp32 -> bf16 RNE (finite inputs only)
__device__ __forceinline__ u16 f2b(float f) {
  u32 u = __float_as_uint(f);
  u = (u + 0x7fffu + ((u >> 16) & 1u)) >> 16;
  return (u16)u;
}

// async global->LDS, 16B per lane. LDS dest must be wave-uniform base + lane*16.
__device__ __forceinline__ void gload16(const void* g, void* l) {
  __builtin_amdgcn_global_load_lds(
      (const __attribute__((address_space(1))) u32*)g,
      (__attribute__((address_space(3))) u32*)l, 16, 0, 0);
}

// ---------------------------------------------------------------------------
// Weight transpose + fp32->bf16. in: [z][R][C] fp32 row-major.
// out element (z,c,r) at out[(z*C + c)*R + r]  (i.e. [N][K] per matrix).
__global__ __launch_bounds__(256)
void transpose_bf16_k(const float* __restrict__ in, u16* __restrict__ out,
                      int R, int C) {
  __shared__ float tile[64][65];
  int r0 = blockIdx.x * 64, c0 = blockIdx.y * 64;
  const float* ip = in + (size_t)blockIdx.z * R * C;
  u16* op = out + (size_t)blockIdx.z * C * R;
  int tr = threadIdx.x >> 6, tc = threadIdx.x & 63;
#pragma unroll
  for (int i = 0; i < 16; i++) {
    int r = i * 4 + tr;
    tile[r][tc] = ip[(size_t)(r0 + r) * C + c0 + tc];
  }
  __syncthreads();
#pragma unroll
  for (int i = 0; i < 16; i++) {
    int c = i * 4 + tr;
    op[(size_t)(c0 + c) * R + r0 + tc] = f2b(tile[tc][c]);
  }
}

// ---------------------------------------------------------------------------
// bf16 transpose for V: vin [bh][2048][64] -> vt [bh][64][2048]
__global__ __launch_bounds__(256)
void vtrans_k(const u16* __restrict__ vin, u16* __restrict__ vt) {
  __shared__ __align__(16) u16 tile[64][72];
  int s0 = blockIdx.x * 64, bh = blockIdx.y;
  const u16* ip = vin + (size_t)bh * 2048 * 64;
  u16* op = vt + (size_t)bh * 64 * 2048;
  int t = threadIdx.x;
#pragma unroll
  for (int i = 0; i < 2; i++) {
    int idx = i * 256 + t, r = idx >> 3, c = idx & 7;
    *(uint4*)&tile[r][c * 8] = *(const uint4*)(ip + (size_t)(s0 + r) * 64 + c * 8);
  }
  __syncthreads();
#pragma unroll
  for (int i = 0; i < 16; i++) {
    int d = i * 4 + (t >> 6), s = t & 63;
    op[(size_t)d * 2048 + s0 + s] = tile[s][d];
  }
}

// ---------------------------------------------------------------------------
// LayerNorm over rows of 1024. Optional second input (residual add) and
// optional fp32 output; always writes bf16 output.
__global__ __launch_bounds__(256)
void ln_k(const float* __restrict__ in, const float* __restrict__ in2,
          const float* __restrict__ w, const float* __restrict__ b,
          float* __restrict__ outf, u16* __restrict__ outb) {
  int row = blockIdx.x, t = threadIdx.x;
  const float4* ip = (const float4*)(in + (size_t)row * 1024);
  float4 x = ip[t];
  if (in2) {
    const float4* ip2 = (const float4*)(in2 + (size_t)row * 1024);
    float4 o = ip2[t];
    x.x += o.x; x.y += o.y; x.z += o.z; x.w += o.w;
  }
  float s = x.x + x.y + x.z + x.w;
  float q = x.x * x.x + x.y * x.y + x.z * x.z + x.w * x.w;
#pragma unroll
  for (int m = 32; m; m >>= 1) { s += __shfl_xor(s, m); q += __shfl_xor(q, m); }
  __shared__ float rs[4], rq[4];
  if ((t & 63) == 0) { rs[t >> 6] = s; rq[t >> 6] = q; }
  __syncthreads();
  s = rs[0] + rs[1] + rs[2] + rs[3];
  q = rq[0] + rq[1] + rq[2] + rq[3];
  float mean = s * (1.f / 1024.f);
  float var  = q * (1.f / 1024.f) - mean * mean;
  float rstd = rsqrtf(var + 1e-5f);
  float4 wv = ((const float4*)w)[t];
  float4 bv = ((const float4*)b)[t];
  float4 y;
  y.x = (x.x - mean) * rstd * wv.x + bv.x;
  y.y = (x.y - mean) * rstd * wv.y + bv.y;
  y.z = (x.z - mean) * rstd * wv.z + bv.z;
  y.w = (x.w - mean) * rstd * wv.w + bv.w;
  if (outf) ((float4*)(outf + (size_t)row * 1024))[t] = y;
  ushort4 ub;
  ub.x = f2b(y.x); ub.y = f2b(y.y); ub.z = f2b(y.z); ub.w = f2b(y.w);
  ((ushort4*)(outb + (size_t)row * 1024))[t] = ub;
}

// ---------------------------------------------------------------------------
// 128x128 tile bf16 GEMM, BK=32, 256 threads (4 waves, 2x2 of 64x64 each).
// A: [M][K] bf16 row-major (lda). Bt: [N][K] bf16 row-major (ldbt).
#define EPI_QKV  0
#define EPI_RELU 1
#define EPI_RES  2

template <int EPI>
__global__ __launch_bounds__(256)
void gemm_k(const u16* __restrict__ A, const u16* __restrict__ Bt,
            int K, int lda, int ldbt,
            const float* __restrict__ bias0, const float* __restrict__ bias1,
            const float* __restrict__ bias2, const float* __restrict__ res,
            int ldout, u16* __restrict__ outb, float* __restrict__ outf) {
  __shared__ __align__(16) u16 As[128 * 32];
  __shared__ __align__(16) u16 Bs[128 * 32];
  int t = threadIdx.x;
  int wave = t >> 6, lane = t & 63, quad = lane >> 4, l16 = lane & 15;
  int wm = (wave >> 1) * 64, wn = (wave & 1) * 64;
  int bm = blockIdx.x * 128, bn = blockIdx.y * 128;

  const u16* Ag = A + (size_t)(bm + (t >> 2)) * lda + (t & 3) * 8;
  const u16* Bg = Bt + (size_t)(bn + (t >> 2)) * ldbt + (t & 3) * 8;
  u16* Asl = As + t * 8;
  u16* Bsl = Bs + t * 8;

  f32x4 acc[4][4] = {};

  for (int k0 = 0; k0 < K; k0 += 32) {
    gload16(Ag + k0, Asl);
    gload16(Ag + k0 + (size_t)64 * lda, Asl + 2048);
    gload16(Bg + k0, Bsl);
    gload16(Bg + k0 + (size_t)64 * ldbt, Bsl + 2048);
    __syncthreads();
    bf16x8 af[4], bfr[4];
#pragma unroll
    for (int i = 0; i < 4; i++)
      af[i] = *(const bf16x8*)(As + (wm + i * 16 + l16) * 32 + quad * 8);
#pragma unroll
    for (int j = 0; j < 4; j++)
      bfr[j] = *(const bf16x8*)(Bs + (wn + j * 16 + l16) * 32 + quad * 8);
#pragma unroll
    for (int i = 0; i < 4; i++)
#pragma unroll
      for (int j = 0; j < 4; j++)
        acc[i][j] = __builtin_amdgcn_mfma_f32_16x16x32_bf16(af[i], bfr[j],
                                                            acc[i][j], 0, 0, 0);
    __syncthreads();
  }

#pragma unroll
  for (int i = 0; i < 4; i++) {
#pragma unroll
    for (int j = 0; j < 4; j++) {
      int c = bn + wn + j * 16 + l16;
#pragma unroll
      for (int rr = 0; rr < 4; rr++) {
        int r = bm + wm + i * 16 + quad * 4 + rr;
        float v = acc[i][j][rr];
        if (EPI == EPI_QKV) {
          int which = c >> 10, h = (c >> 6) & 15, d = c & 63;
          const float* bp = which == 0 ? bias0 : (which == 1 ? bias1 : bias2);
          v += bp[h * 64 + d];
          int bb = r >> 11, ss = r & 2047;
          outb[((size_t)(which * 32 + bb * 16 + h) * 2048 + ss) * 64 + d] = f2b(v);
        } else if (EPI == EPI_RELU) {
          v += bias0[c];
          v = v > 0.f ? v : 0.f;
          outb[(size_t)r * ldout + c] = f2b(v);
        } else {
          v += bias0[c] + res[(size_t)r * ldout + c];
          outf[(size_t)r * ldout + c] = v;
        }
      }
    }
  }
}

// ---------------------------------------------------------------------------
// Flash attention, causal. Grid (16, 32) blocks of 512 threads (8 waves).
// Q tile = 128 rows; wave w owns rows [w*16, w*16+16). Online softmax fully
// in registers; P transposed through per-wave LDS (no barrier); K/V double-
// buffered via gload16 with XOR-swizzled chunks (conflict-free b128 reads).
// qkv: [which*32+bh][2048][64] bf16.  vt: [bh][64][2048] bf16.
// o: [B][S][1024] fp32 (head-concat).
__global__ __launch_bounds__(512, 4)
void attn_k(const u16* __restrict__ qkv, const u16* __restrict__ vt,
            float* __restrict__ o) {
  int bh = blockIdx.y;
  // complementary pairing: blocks b and b+256 (same CU under round-robin)
  // get Qt = x and 15-x, balancing causal work.
  int Qt = (bh >> 4) ? (15 - (int)blockIdx.x) : (int)blockIdx.x;
  int b = bh >> 4, h = bh & 15;
  const u16* qg = qkv + (size_t)bh * (2048 * 64) + (size_t)Qt * 128 * 64;
  const u16* kg = qkv + (size_t)(32 + bh) * (2048 * 64);
  const u16* vg = vt + (size_t)bh * (64 * 2048);

  __shared__ __align__(16) u16 Qs[128 * 64];
  __shared__ __align__(16) u16 Ks[2][64 * 64];
  __shared__ __align__(16) u16 Vs[2][64 * 64];
  __shared__ __align__(16) u16 Ps[8][16 * 64];

  int t = threadIdx.x;
  int wave = t >> 6, lane = t & 63, quad = lane >> 4, l16 = lane & 15;

  // stage Q (chunk-swizzled) + K/V tile 0
  {
#pragma unroll
    for (int i = 0; i < 2; i++) {
      int idx = i * 512 + t, r = idx >> 3, c = (idx & 7) ^ (r & 7);
      gload16(qg + r * 64 + c * 8, Qs + idx * 8);
    }
    int r = t >> 3, c = (t & 7) ^ (r & 7);
    gload16(kg + (size_t)r * 64 + c * 8, Ks[0] + t * 8);
    gload16(vg + (size_t)r * 2048 + c * 8, Vs[0] + t * 8);
  }
  __syncthreads();

  int x7 = l16 & 7;
  bf16x8 qf[2];
  {
    const u16* qr = Qs + (wave * 16 + l16) * 64;
    qf[0] = *(const bf16x8*)(qr + ((quad ^ x7) * 8));
    qf[1] = *(const bf16x8*)(qr + (((4 + quad) ^ x7) * 8));
  }

  f32x4 oacc[4] = {};
  float mo[4] = {NEG_INF, NEG_INF, NEG_INF, NEG_INF};
  float ll[4] = {};
  u16* Pw = Ps[wave];
  int rmin = Qt * 128 + wave * 16;
  int kmax_w = (rmin + 15) >> 6;
  int klast = 2 * Qt + 1;

  for (int kt = 0; kt <= klast; kt++) {
    const u16* ks = Ks[kt & 1];
    const u16* vs = Vs[kt & 1];
    if (kt < klast) {  // prefetch next tile into other buffer
      int r = t >> 3, c = (t & 7) ^ (r & 7);
      gload16(kg + (size_t)((kt + 1) * 64 + r) * 64 + c * 8, Ks[(kt + 1) & 1] + t * 8);
      gload16(vg + (size_t)r * 2048 + (kt + 1) * 64 + c * 8, Vs[(kt + 1) & 1] + t * 8);
    }
    if (kt <= kmax_w) {
      // ---- S = Q K^T (wave's 16 rows x 64 kv cols) ----
      f32x4 sc[4];
#pragma unroll
      for (int g = 0; g < 4; g++) {
        const u16* kr = ks + (g * 16 + l16) * 64;
        bf16x8 kf0 = *(const bf16x8*)(kr + ((quad ^ x7) * 8));
        bf16x8 kf1 = *(const bf16x8*)(kr + (((4 + quad) ^ x7) * 8));
        f32x4 s = {};
        s = __builtin_amdgcn_mfma_f32_16x16x32_bf16(qf[0], kf0, s, 0, 0, 0);
        s = __builtin_amdgcn_mfma_f32_16x16x32_bf16(qf[1], kf1, s, 0, 0, 0);
        sc[g] = s;
      }
      // ---- scale + causal mask ----
      if (kt * 64 + 63 > rmin) {
#pragma unroll
        for (int g = 0; g < 4; g++) {
          int col = kt * 64 + g * 16 + l16;
#pragma unroll
          for (int rr = 0; rr < 4; rr++) {
            int row = rmin + quad * 4 + rr;
            sc[g][rr] = (col <= row) ? sc[g][rr] * 0.125f : NEG_INF;
          }
        }
      } else {
#pragma unroll
        for (int g = 0; g < 4; g++)
#pragma unroll
          for (int rr = 0; rr < 4; rr++) sc[g][rr] *= 0.125f;
      }
      // ---- online softmax (in-register, 16-lane reductions) ----
      float al[4], rsum[4];
#pragma unroll
      for (int rr = 0; rr < 4; rr++) {
        float mx = fmaxf(fmaxf(sc[0][rr], sc[1][rr]), fmaxf(sc[2][rr], sc[3][rr]));
        mx = fmaxf(mx, __shfl_xor(mx, 1));
        mx = fmaxf(mx, __shfl_xor(mx, 2));
        mx = fmaxf(mx, __shfl_xor(mx, 4));
        mx = fmaxf(mx, __shfl_xor(mx, 8));
        float mnew = fmaxf(mo[rr], mx);
        al[rr] = __expf(mo[rr] - mnew);
        mo[rr] = mnew;
        rsum[rr] = 0.f;
      }
      // p = exp(sc - m), write P strip (swizzled, wave-private: no barrier)
#pragma unroll
      for (int g = 0; g < 4; g++) {
        int cbase = (g * 16 + l16 + quad * 16) & 63;
#pragma unroll
        for (int rr = 0; rr < 4; rr++) {
          float p = __expf(sc[g][rr] - mo[rr]);
          rsum[rr] += p;
          Pw[(quad * 4 + rr) * 64 + cbase] = f2b(p);
        }
      }
#pragma unroll
      for (int rr = 0; rr < 4; rr++) {
        rsum[rr] += __shfl_xor(rsum[rr], 1);
        rsum[rr] += __shfl_xor(rsum[rr], 2);
        rsum[rr] += __shfl_xor(rsum[rr], 4);
        rsum[rr] += __shfl_xor(rsum[rr], 8);
        ll[rr] = ll[rr] * al[rr] + rsum[rr];
      }
#pragma unroll
      for (int g = 0; g < 4; g++)
#pragma unroll
        for (int rr = 0; rr < 4; rr++) oacc[g][rr] *= al[rr];
      // ---- O += P V ----
      bf16x8 pf0, pf1;
      {
        const u16* pr = Pw + l16 * 64;
        int sh = (l16 & 12) * 4;
        pf0 = *(const bf16x8*)(pr + ((quad * 8 + sh) & 63));
        pf1 = *(const bf16x8*)(pr + ((32 + quad * 8 + sh) & 63));
      }
#pragma unroll
      for (int g = 0; g < 4; g++) {
        const u16* vr = vs + (g * 16 + l16) * 64;
        bf16x8 vf0 = *(const bf16x8*)(vr + ((quad ^ x7) * 8));
        bf16x8 vf1 = *(const bf16x8*)(vr + (((4 + quad) ^ x7) * 8));
        oacc[g] = __builtin_amdgcn_mfma_f32_16x16x32_bf16(pf0, vf0, oacc[g], 0, 0, 0);
        oacc[g] = __builtin_amdgcn_mfma_f32_16x16x32_bf16(pf1, vf1, oacc[g], 0, 0, 0);
      }
    }
    __syncthreads();
  }

  // normalize and write O (head-concat layout)
#pragma unroll
  for (int g = 0; g < 4; g++)
#pragma unroll
    for (int rr = 0; rr < 4; rr++) {
      int srow = rmin + quad * 4 + rr;
      o[((size_t)b * 2048 + srow) * 1024 + h * 64 + g * 16 + l16] =
          oacc[g][rr] / ll[rr];
    }
}

// ---------------------------------------------------------------------------
extern "C" void kernel_launch(void* const* d_in, const int* in_sizes, int n_in,
                              void* d_out, int out_size, void* d_ws, size_t ws_size,
                              hipStream_t stream) {
  const float* emb  = (const float*)d_in[0];
  const float* Wq   = (const float*)d_in[1];
  const float* bq   = (const float*)d_in[2];
  const float* Wk   = (const float*)d_in[3];
  const float* bk   = (const float*)d_in[4];
  const float* Wv   = (const float*)d_in[5];
  const float* bv   = (const float*)d_in[6];
  const float* ln1w = (const float*)d_in[7];
  const float* ln1b = (const float*)d_in[8];
  const float* ln2w = (const float*)d_in[9];
  const float* ln2b = (const float*)d_in[10];
  const float* W1   = (const float*)d_in[11];
  const float* b1   = (const float*)d_in[12];
  const float* W2   = (const float*)d_in[13];
  const float* b2   = (const float*)d_in[14];
  float* out = (float*)d_out;

  char* p = (char*)d_ws;
  u16*   Wqkv_t = (u16*)p;   p += (size_t)3072 * 1024 * 2;
  u16*   W1t    = (u16*)p;   p += (size_t)4096 * 1024 * 2;
  u16*   W2t    = (u16*)p;   p += (size_t)1024 * 4096 * 2;
  float* x      = (float*)p; p += (size_t)4096 * 1024 * 4;
  u16*   xb     = (u16*)p;   p += (size_t)4096 * 1024 * 2;
  u16*   qkvb   = (u16*)p;   p += (size_t)3 * 32 * 2048 * 64 * 2;  // 25.2 MB
  float* ob     = (float*)p; p += (size_t)4096 * 1024 * 4;         // 16.8 MB
  float* y      = (float*)p; p += (size_t)4096 * 1024 * 4;
  u16*   yb     = (u16*)p;   p += (size_t)4096 * 1024 * 2;
  u16*   hb     = (u16*)qkvb; // alias: qkvb+ob (42 MB) dead before FFN1 writes hb (33.6 MB)
  u16*   vT     = (u16*)y;    // alias: vT (8.4 MB) dead before ln2 writes y
  if (ws_size < (size_t)(p - (char*)d_ws)) return;

  // weight transposes (d_ws poisoned each call -> must rebuild every launch)
  transpose_bf16_k<<<dim3(16, 1, 16), 256, 0, stream>>>(Wq, Wqkv_t,                   1024, 64);
  transpose_bf16_k<<<dim3(16, 1, 16), 256, 0, stream>>>(Wk, Wqkv_t + 1024 * 1024,     1024, 64);
  transpose_bf16_k<<<dim3(16, 1, 16), 256, 0, stream>>>(Wv, Wqkv_t + 2 * 1024 * 1024, 1024, 64);
  transpose_bf16_k<<<dim3(16, 64, 1), 256, 0, stream>>>(W1, W1t, 1024, 4096);
  transpose_bf16_k<<<dim3(64, 16, 1), 256, 0, stream>>>(W2, W2t, 4096, 1024);

  ln_k<<<dim3(4096), 256, 0, stream>>>(emb, nullptr, ln1w, ln1b, x, xb);

  gemm_k<EPI_QKV><<<dim3(32, 24), 256, 0, stream>>>(
      xb, Wqkv_t, 1024, 1024, 1024, bq, bk, bv, nullptr, 0, qkvb, nullptr);

  vtrans_k<<<dim3(32, 32), 256, 0, stream>>>(qkvb + (size_t)64 * 2048 * 64, vT);

  attn_k<<<dim3(16, 32), 512, 0, stream>>>(qkvb, vT, ob);

  ln_k<<<dim3(4096), 256, 0, stream>>>(x, ob, ln2w, ln2b, y, yb);

  gemm_k<EPI_RELU><<<dim3(32, 32), 256, 0, stream>>>(
      yb, W1t, 1024, 1024, 1024, b1, nullptr, nullptr, nullptr, 4096, hb, nullptr);

  gemm_k<EPI_RES><<<dim3(32, 8), 256, 0, stream>>>(
      hb, W2t, 4096, 4096, 4096, b2, nullptr, nullptr, y, 1024, nullptr, out);
}

// Round 3
// 359.436 us; speedup vs baseline: 1.4023x; 1.0959x over previous
//
#include <hip/hip_runtime.h>

// TransformerLayer on MI355X (gfx950), bf16 MFMA pipeline, fp32 LN/softmax/accum.
// R3: GEMM v2 — BK=64 with XOR chunk swizzle (conflict-free ds_read_b128,
// same scheme as the verified R2 attention), FFN2 split-K=2 (z1 partial into
// dead `x` buffer, deterministic reduce kernel adds it into out).

typedef unsigned short u16;
typedef unsigned int   u32;
typedef __bf16 bf16x8 __attribute__((ext_vector_type(8)));
typedef float  f32x4  __attribute__((ext_vector_type(4)));

#define NEG_INF (-__builtin_inff())

// fp32 -> bf16 RNE (finite inputs only)
__device__ __forceinline__ u16 f2b(float f) {
  u32 u = __float_as_uint(f);
  u = (u + 0x7fffu + ((u >> 16) & 1u)) >> 16;
  return (u16)u;
}

// async global->LDS, 16B per lane. LDS dest must be wave-uniform base + lane*16.
__device__ __forceinline__ void gload16(const void* g, void* l) {
  __builtin_amdgcn_global_load_lds(
      (const __attribute__((address_space(1))) u32*)g,
      (__attribute__((address_space(3))) u32*)l, 16, 0, 0);
}

// ---------------------------------------------------------------------------
// Weight transpose + fp32->bf16. in: [z][R][C] fp32 row-major.
// out element (z,c,r) at out[(z*C + c)*R + r]  (i.e. [N][K] per matrix).
__global__ __launch_bounds__(256)
void transpose_bf16_k(const float* __restrict__ in, u16* __restrict__ out,
                      int R, int C) {
  __shared__ float tile[64][65];
  int r0 = blockIdx.x * 64, c0 = blockIdx.y * 64;
  const float* ip = in + (size_t)blockIdx.z * R * C;
  u16* op = out + (size_t)blockIdx.z * C * R;
  int tr = threadIdx.x >> 6, tc = threadIdx.x & 63;
#pragma unroll
  for (int i = 0; i < 16; i++) {
    int r = i * 4 + tr;
    tile[r][tc] = ip[(size_t)(r0 + r) * C + c0 + tc];
  }
  __syncthreads();
#pragma unroll
  for (int i = 0; i < 16; i++) {
    int c = i * 4 + tr;
    op[(size_t)(c0 + c) * R + r0 + tc] = f2b(tile[tc][c]);
  }
}

// ---------------------------------------------------------------------------
// bf16 transpose for V: vin [bh][2048][64] -> vt [bh][64][2048]
__global__ __launch_bounds__(256)
void vtrans_k(const u16* __restrict__ vin, u16* __restrict__ vt) {
  __shared__ __align__(16) u16 tile[64][72];
  int s0 = blockIdx.x * 64, bh = blockIdx.y;
  const u16* ip = vin + (size_t)bh * 2048 * 64;
  u16* op = vt + (size_t)bh * 64 * 2048;
  int t = threadIdx.x;
#pragma unroll
  for (int i = 0; i < 2; i++) {
    int idx = i * 256 + t, r = idx >> 3, c = idx & 7;
    *(uint4*)&tile[r][c * 8] = *(const uint4*)(ip + (size_t)(s0 + r) * 64 + c * 8);
  }
  __syncthreads();
#pragma unroll
  for (int i = 0; i < 16; i++) {
    int d = i * 4 + (t >> 6), s = t & 63;
    op[(size_t)d * 2048 + s0 + s] = tile[s][d];
  }
}

// ---------------------------------------------------------------------------
// LayerNorm over rows of 1024. Optional second input (residual add) and
// optional fp32 output; always writes bf16 output.
__global__ __launch_bounds__(256)
void ln_k(const float* __restrict__ in, const float* __restrict__ in2,
          const float* __restrict__ w, const float* __restrict__ b,
          float* __restrict__ outf, u16* __restrict__ outb) {
  int row = blockIdx.x, t = threadIdx.x;
  const float4* ip = (const float4*)(in + (size_t)row * 1024);
  float4 x = ip[t];
  if (in2) {
    const float4* ip2 = (const float4*)(in2 + (size_t)row * 1024);
    float4 o = ip2[t];
    x.x += o.x; x.y += o.y; x.z += o.z; x.w += o.w;
  }
  float s = x.x + x.y + x.z + x.w;
  float q = x.x * x.x + x.y * x.y + x.z * x.z + x.w * x.w;
#pragma unroll
  for (int m = 32; m; m >>= 1) { s += __shfl_xor(s, m); q += __shfl_xor(q, m); }
  __shared__ float rs[4], rq[4];
  if ((t & 63) == 0) { rs[t >> 6] = s; rq[t >> 6] = q; }
  __syncthreads();
  s = rs[0] + rs[1] + rs[2] + rs[3];
  q = rq[0] + rq[1] + rq[2] + rq[3];
  float mean = s * (1.f / 1024.f);
  float var  = q * (1.f / 1024.f) - mean * mean;
  float rstd = rsqrtf(var + 1e-5f);
  float4 wv = ((const float4*)w)[t];
  float4 bv = ((const float4*)b)[t];
  float4 y;
  y.x = (x.x - mean) * rstd * wv.x + bv.x;
  y.y = (x.y - mean) * rstd * wv.y + bv.y;
  y.z = (x.z - mean) * rstd * wv.z + bv.z;
  y.w = (x.w - mean) * rstd * wv.w + bv.w;
  if (outf) ((float4*)(outf + (size_t)row * 1024))[t] = y;
  ushort4 ub;
  ub.x = f2b(y.x); ub.y = f2b(y.y); ub.z = f2b(y.z); ub.w = f2b(y.w);
  ((ushort4*)(outb + (size_t)row * 1024))[t] = ub;
}

// ---------------------------------------------------------------------------
// 128x128 tile bf16 GEMM v2, BK=64, 256 threads (4 waves, 2x2 of 64x64 each).
// A: [M][K] bf16 row-major (lda). Bt: [N][K] bf16 row-major (ldbt).
// LDS rows are 8 chunks of 16B; chunk c of row r stored at slot c^(r&7)
// (swizzle applied to the GLOBAL source address; gload16 dest stays
// lane-linear). Frag reads are conflict-free ds_read_b128.
// blockIdx.z = K-slice (split-K): z>0 writes raw partial to outp.
#define EPI_QKV  0
#define EPI_RELU 1
#define EPI_RES  2

template <int EPI>
__global__ __launch_bounds__(256)
void gemm_k(const u16* __restrict__ A, const u16* __restrict__ Bt,
            int K, int lda, int ldbt,
            const float* __restrict__ bias0, const float* __restrict__ bias1,
            const float* __restrict__ bias2, const float* __restrict__ res,
            int ldout, u16* __restrict__ outb, float* __restrict__ outf,
            float* __restrict__ outp) {
  __shared__ __align__(16) u16 As[128 * 64];
  __shared__ __align__(16) u16 Bs[128 * 64];
  int t = threadIdx.x;
  int wave = t >> 6, lane = t & 63, quad = lane >> 4, l16 = lane & 15;
  int x7 = l16 & 7;
  int wm = (wave >> 1) * 64, wn = (wave & 1) * 64;
  int bm = blockIdx.x * 128, bn = blockIdx.y * 128;
  int zoff = blockIdx.z * K;

  // staging: thread t owns LDS slots idx = i*256+t (i=0..3) per matrix.
  // slot idx -> row r=idx>>3, slot s=idx&7 holds global chunk s^(r&7).
  const u16* Agl[4];
  const u16* Bgl[4];
#pragma unroll
  for (int i = 0; i < 4; i++) {
    int idx = i * 256 + t, r = idx >> 3, c = (idx & 7) ^ (r & 7);
    Agl[i] = A + (size_t)(bm + r) * lda + zoff + c * 8;
    Bgl[i] = Bt + (size_t)(bn + r) * ldbt + zoff + c * 8;
  }
  u16* Asl = As + t * 8;
  u16* Bsl = Bs + t * 8;

  f32x4 acc[4][4] = {};

  for (int k0 = 0; k0 < K; k0 += 64) {
#pragma unroll
    for (int i = 0; i < 4; i++) {
      gload16(Agl[i] + k0, Asl + i * 2048);
      gload16(Bgl[i] + k0, Bsl + i * 2048);
    }
    __syncthreads();
#pragma unroll
    for (int kc = 0; kc < 2; kc++) {
      bf16x8 af[4], bfr[4];
#pragma unroll
      for (int i = 0; i < 4; i++) {
        int r = wm + i * 16 + l16;
        af[i] = *(const bf16x8*)(As + r * 64 + (((kc * 4 + quad) ^ x7) * 8));
      }
#pragma unroll
      for (int j = 0; j < 4; j++) {
        int r = wn + j * 16 + l16;
        bfr[j] = *(const bf16x8*)(Bs + r * 64 + (((kc * 4 + quad) ^ x7) * 8));
      }
#pragma unroll
      for (int i = 0; i < 4; i++)
#pragma unroll
        for (int j = 0; j < 4; j++)
          acc[i][j] = __builtin_amdgcn_mfma_f32_16x16x32_bf16(af[i], bfr[j],
                                                              acc[i][j], 0, 0, 0);
    }
    __syncthreads();
  }

#pragma unroll
  for (int i = 0; i < 4; i++) {
#pragma unroll
    for (int j = 0; j < 4; j++) {
      int c = bn + wn + j * 16 + l16;
#pragma unroll
      for (int rr = 0; rr < 4; rr++) {
        int r = bm + wm + i * 16 + quad * 4 + rr;
        float v = acc[i][j][rr];
        if (EPI == EPI_QKV) {
          int which = c >> 10, h = (c >> 6) & 15, d = c & 63;
          const float* bp = which == 0 ? bias0 : (which == 1 ? bias1 : bias2);
          v += bp[h * 64 + d];
          int bb = r >> 11, ss = r & 2047;
          outb[((size_t)(which * 32 + bb * 16 + h) * 2048 + ss) * 64 + d] = f2b(v);
        } else if (EPI == EPI_RELU) {
          v += bias0[c];
          v = v > 0.f ? v : 0.f;
          outb[(size_t)r * ldout + c] = f2b(v);
        } else {
          if (blockIdx.z == 0) {
            v += bias0[c] + res[(size_t)r * ldout + c];
            outf[(size_t)r * ldout + c] = v;
          } else {
            outp[(size_t)r * ldout + c] = v;
          }
        }
      }
    }
  }
}

// out[i] += part[i]  (fp32, float4)
__global__ __launch_bounds__(256)
void reduce_k(float* __restrict__ out, const float* __restrict__ part) {
  int i = blockIdx.x * 256 + threadIdx.x;
  float4 a = ((const float4*)part)[i];
  float4 b = ((float4*)out)[i];
  b.x += a.x; b.y += a.y; b.z += a.z; b.w += a.w;
  ((float4*)out)[i] = b;
}

// ---------------------------------------------------------------------------
// Flash attention, causal. Grid (16, 32) blocks of 512 threads (8 waves).
// (unchanged from R2 — verified)
__global__ __launch_bounds__(512, 4)
void attn_k(const u16* __restrict__ qkv, const u16* __restrict__ vt,
            float* __restrict__ o) {
  int bh = blockIdx.y;
  int Qt = (bh >> 4) ? (15 - (int)blockIdx.x) : (int)blockIdx.x;
  int b = bh >> 4, h = bh & 15;
  const u16* qg = qkv + (size_t)bh * (2048 * 64) + (size_t)Qt * 128 * 64;
  const u16* kg = qkv + (size_t)(32 + bh) * (2048 * 64);
  const u16* vg = vt + (size_t)bh * (64 * 2048);

  __shared__ __align__(16) u16 Qs[128 * 64];
  __shared__ __align__(16) u16 Ks[2][64 * 64];
  __shared__ __align__(16) u16 Vs[2][64 * 64];
  __shared__ __align__(16) u16 Ps[8][16 * 64];

  int t = threadIdx.x;
  int wave = t >> 6, lane = t & 63, quad = lane >> 4, l16 = lane & 15;

  {
#pragma unroll
    for (int i = 0; i < 2; i++) {
      int idx = i * 512 + t, r = idx >> 3, c = (idx & 7) ^ (r & 7);
      gload16(qg + r * 64 + c * 8, Qs + idx * 8);
    }
    int r = t >> 3, c = (t & 7) ^ (r & 7);
    gload16(kg + (size_t)r * 64 + c * 8, Ks[0] + t * 8);
    gload16(vg + (size_t)r * 2048 + c * 8, Vs[0] + t * 8);
  }
  __syncthreads();

  int x7 = l16 & 7;
  bf16x8 qf[2];
  {
    const u16* qr = Qs + (wave * 16 + l16) * 64;
    qf[0] = *(const bf16x8*)(qr + ((quad ^ x7) * 8));
    qf[1] = *(const bf16x8*)(qr + (((4 + quad) ^ x7) * 8));
  }

  f32x4 oacc[4] = {};
  float mo[4] = {NEG_INF, NEG_INF, NEG_INF, NEG_INF};
  float ll[4] = {};
  u16* Pw = Ps[wave];
  int rmin = Qt * 128 + wave * 16;
  int kmax_w = (rmin + 15) >> 6;
  int klast = 2 * Qt + 1;

  for (int kt = 0; kt <= klast; kt++) {
    const u16* ks = Ks[kt & 1];
    const u16* vs = Vs[kt & 1];
    if (kt < klast) {
      int r = t >> 3, c = (t & 7) ^ (r & 7);
      gload16(kg + (size_t)((kt + 1) * 64 + r) * 64 + c * 8, Ks[(kt + 1) & 1] + t * 8);
      gload16(vg + (size_t)r * 2048 + (kt + 1) * 64 + c * 8, Vs[(kt + 1) & 1] + t * 8);
    }
    if (kt <= kmax_w) {
      f32x4 sc[4];
#pragma unroll
      for (int g = 0; g < 4; g++) {
        const u16* kr = ks + (g * 16 + l16) * 64;
        bf16x8 kf0 = *(const bf16x8*)(kr + ((quad ^ x7) * 8));
        bf16x8 kf1 = *(const bf16x8*)(kr + (((4 + quad) ^ x7) * 8));
        f32x4 s = {};
        s = __builtin_amdgcn_mfma_f32_16x16x32_bf16(qf[0], kf0, s, 0, 0, 0);
        s = __builtin_amdgcn_mfma_f32_16x16x32_bf16(qf[1], kf1, s, 0, 0, 0);
        sc[g] = s;
      }
      if (kt * 64 + 63 > rmin) {
#pragma unroll
        for (int g = 0; g < 4; g++) {
          int col = kt * 64 + g * 16 + l16;
#pragma unroll
          for (int rr = 0; rr < 4; rr++) {
            int row = rmin + quad * 4 + rr;
            sc[g][rr] = (col <= row) ? sc[g][rr] * 0.125f : NEG_INF;
          }
        }
      } else {
#pragma unroll
        for (int g = 0; g < 4; g++)
#pragma unroll
          for (int rr = 0; rr < 4; rr++) sc[g][rr] *= 0.125f;
      }
      float al[4], rsum[4];
#pragma unroll
      for (int rr = 0; rr < 4; rr++) {
        float mx = fmaxf(fmaxf(sc[0][rr], sc[1][rr]), fmaxf(sc[2][rr], sc[3][rr]));
        mx = fmaxf(mx, __shfl_xor(mx, 1));
        mx = fmaxf(mx, __shfl_xor(mx, 2));
        mx = fmaxf(mx, __shfl_xor(mx, 4));
        mx = fmaxf(mx, __shfl_xor(mx, 8));
        float mnew = fmaxf(mo[rr], mx);
        al[rr] = __expf(mo[rr] - mnew);
        mo[rr] = mnew;
        rsum[rr] = 0.f;
      }
#pragma unroll
      for (int g = 0; g < 4; g++) {
        int cbase = (g * 16 + l16 + quad * 16) & 63;
#pragma unroll
        for (int rr = 0; rr < 4; rr++) {
          float p = __expf(sc[g][rr] - mo[rr]);
          rsum[rr] += p;
          Pw[(quad * 4 + rr) * 64 + cbase] = f2b(p);
        }
      }
#pragma unroll
      for (int rr = 0; rr < 4; rr++) {
        rsum[rr] += __shfl_xor(rsum[rr], 1);
        rsum[rr] += __shfl_xor(rsum[rr], 2);
        rsum[rr] += __shfl_xor(rsum[rr], 4);
        rsum[rr] += __shfl_xor(rsum[rr], 8);
        ll[rr] = ll[rr] * al[rr] + rsum[rr];
      }
#pragma unroll
      for (int g = 0; g < 4; g++)
#pragma unroll
        for (int rr = 0; rr < 4; rr++) oacc[g][rr] *= al[rr];
      bf16x8 pf0, pf1;
      {
        const u16* pr = Pw + l16 * 64;
        int sh = (l16 & 12) * 4;
        pf0 = *(const bf16x8*)(pr + ((quad * 8 + sh) & 63));
        pf1 = *(const bf16x8*)(pr + ((32 + quad * 8 + sh) & 63));
      }
#pragma unroll
      for (int g = 0; g < 4; g++) {
        const u16* vr = vs + (g * 16 + l16) * 64;
        bf16x8 vf0 = *(const bf16x8*)(vr + ((quad ^ x7) * 8));
        bf16x8 vf1 = *(const bf16x8*)(vr + (((4 + quad) ^ x7) * 8));
        oacc[g] = __builtin_amdgcn_mfma_f32_16x16x32_bf16(pf0, vf0, oacc[g], 0, 0, 0);
        oacc[g] = __builtin_amdgcn_mfma_f32_16x16x32_bf16(pf1, vf1, oacc[g], 0, 0, 0);
      }
    }
    __syncthreads();
  }

#pragma unroll
  for (int g = 0; g < 4; g++)
#pragma unroll
    for (int rr = 0; rr < 4; rr++) {
      int srow = rmin + quad * 4 + rr;
      o[((size_t)b * 2048 + srow) * 1024 + h * 64 + g * 16 + l16] =
          oacc[g][rr] / ll[rr];
    }
}

// ---------------------------------------------------------------------------
extern "C" void kernel_launch(void* const* d_in, const int* in_sizes, int n_in,
                              void* d_out, int out_size, void* d_ws, size_t ws_size,
                              hipStream_t stream) {
  const float* emb  = (const float*)d_in[0];
  const float* Wq   = (const float*)d_in[1];
  const float* bq   = (const float*)d_in[2];
  const float* Wk   = (const float*)d_in[3];
  const float* bk   = (const float*)d_in[4];
  const float* Wv   = (const float*)d_in[5];
  const float* bv   = (const float*)d_in[6];
  const float* ln1w = (const float*)d_in[7];
  const float* ln1b = (const float*)d_in[8];
  const float* ln2w = (const float*)d_in[9];
  const float* ln2b = (const float*)d_in[10];
  const float* W1   = (const float*)d_in[11];
  const float* b1   = (const float*)d_in[12];
  const float* W2   = (const float*)d_in[13];
  const float* b2   = (const float*)d_in[14];
  float* out = (float*)d_out;

  char* p = (char*)d_ws;
  u16*   Wqkv_t = (u16*)p;   p += (size_t)3072 * 1024 * 2;
  u16*   W1t    = (u16*)p;   p += (size_t)4096 * 1024 * 2;
  u16*   W2t    = (u16*)p;   p += (size_t)1024 * 4096 * 2;
  float* x      = (float*)p; p += (size_t)4096 * 1024 * 4;
  u16*   xb     = (u16*)p;   p += (size_t)4096 * 1024 * 2;
  u16*   qkvb   = (u16*)p;   p += (size_t)3 * 32 * 2048 * 64 * 2;  // 25.2 MB
  float* ob     = (float*)p; p += (size_t)4096 * 1024 * 4;         // 16.8 MB
  float* y      = (float*)p; p += (size_t)4096 * 1024 * 4;
  u16*   yb     = (u16*)p;   p += (size_t)4096 * 1024 * 2;
  u16*   hb     = (u16*)qkvb; // alias: qkvb+ob (42 MB) dead before FFN1 writes hb (33.6 MB)
  u16*   vT     = (u16*)y;    // alias: vT (8.4 MB) dead before ln2 writes y
  float* part   = x;          // alias: x (16.8 MB fp32) dead before FFN2 z=1 partial
  if (ws_size < (size_t)(p - (char*)d_ws)) return;

  transpose_bf16_k<<<dim3(16, 1, 16), 256, 0, stream>>>(Wq, Wqkv_t,                   1024, 64);
  transpose_bf16_k<<<dim3(16, 1, 16), 256, 0, stream>>>(Wk, Wqkv_t + 1024 * 1024,     1024, 64);
  transpose_bf16_k<<<dim3(16, 1, 16), 256, 0, stream>>>(Wv, Wqkv_t + 2 * 1024 * 1024, 1024, 64);
  transpose_bf16_k<<<dim3(16, 64, 1), 256, 0, stream>>>(W1, W1t, 1024, 4096);
  transpose_bf16_k<<<dim3(64, 16, 1), 256, 0, stream>>>(W2, W2t, 4096, 1024);

  ln_k<<<dim3(4096), 256, 0, stream>>>(emb, nullptr, ln1w, ln1b, x, xb);

  gemm_k<EPI_QKV><<<dim3(32, 24, 1), 256, 0, stream>>>(
      xb, Wqkv_t, 1024, 1024, 1024, bq, bk, bv, nullptr, 0, qkvb, nullptr, nullptr);

  vtrans_k<<<dim3(32, 32), 256, 0, stream>>>(qkvb + (size_t)64 * 2048 * 64, vT);

  attn_k<<<dim3(16, 32), 512, 0, stream>>>(qkvb, vT, ob);

  ln_k<<<dim3(4096), 256, 0, stream>>>(x, ob, ln2w, ln2b, y, yb);

  gemm_k<EPI_RELU><<<dim3(32, 32, 1), 256, 0, stream>>>(
      yb, W1t, 1024, 1024, 1024, b1, nullptr, nullptr, nullptr, 4096, hb, nullptr, nullptr);

  // FFN2 split-K=2: z=0 -> out (+b2+y), z=1 -> raw partial into `part`
  gemm_k<EPI_RES><<<dim3(32, 8, 2), 256, 0, stream>>>(
      hb, W2t, 2048, 4096, 4096, b2, nullptr, nullptr, y, 1024, nullptr, out, part);

  reduce_k<<<dim3(4096), 256, 0, stream>>>(out, part);
}